// Round 2
// 292.316 us; speedup vs baseline: 1.0328x; 1.0328x over previous
//
#include <hip/hip_runtime.h>
#include <math.h>

#define EPS 1e-15f
#define BND (1.0f - 1e-7f)

constexpr int B = 64, S = 256, H = 768, D = 64, NEG = 4;
constexpr int NVEC = B + B + B * NEG; // 384 selected vectors

// Reduce across a 64-lane wave; result broadcast to all lanes.
__device__ inline float wave_red(float v) {
#pragma unroll
  for (int o = 32; o > 0; o >>= 1) v += __shfl_down(v, o, 64);
  return __shfl(v, 0, 64);
}

__device__ inline float dot4(float4 a, float4 b) {
  return a.x * b.x + a.y * b.y + a.z * b.z + a.w * b.w;
}

// One block per selected vector: scan one-hot mask row -> gather encoded row
// -> expmap0 -> mobius_matvec(W, .) -> write [D] vector to workspace.
// W access is coalesced: wave w owns output rows d = w*16..w*16+15; lanes
// read consecutive float4s of each W row; xs is register-cached per wave.
__global__ __launch_bounds__(256) void gather_matvec_kernel(
    const float* __restrict__ encoded, const float* __restrict__ n_encoded,
    const float* __restrict__ mask1, const float* __restrict__ mask2,
    const float* __restrict__ mask_u_neg, const float* __restrict__ W,
    float* __restrict__ out_vecs) {
  __shared__ float xs[H];   // gathered raw row
  __shared__ float pm[D];   // matvec results per output dim
  __shared__ int s_idx;
  __shared__ float s_ssq;
  __shared__ float red[4];

  const int i = blockIdx.x;
  const int t = threadIdx.x;
  const int lane = t & 63, w = t >> 6;

  const float* mask;
  const float* src;
  if (i < B) {
    mask = mask1 + (size_t)i * S;
    src = encoded + (size_t)i * S * H;
  } else if (i < 2 * B) {
    mask = mask2 + (size_t)(i - B) * S;
    src = encoded + (size_t)(i - B) * S * H;
  } else {
    mask = mask_u_neg + (size_t)(i - 2 * B) * S;
    src = n_encoded + (size_t)(i - 2 * B) * S * H;
  }

  if (t == 0) s_idx = 0;
  __syncthreads();
  if (mask[t] > 0.5f) s_idx = t;  // one-hot: exactly one thread writes
  __syncthreads();
  const float* row = src + (size_t)s_idx * H;

  // Vectorized gather: 192 float4 = 768 floats. Threads 192..255 idle here.
  float ssq = 0.f;
  if (t < H / 4) {
    float4 v = ((const float4*)row)[t];
    ((float4*)xs)[t] = v;
    ssq = dot4(v, v);
  }
  float wsum = wave_red(ssq);
  if (lane == 0) red[w] = wsum;
  __syncthreads();
  if (t == 0) s_ssq = red[0] + red[1] + red[2] + red[3];
  __syncthreads();

  const float n = sqrtf(s_ssq);
  const float n_cl = fmaxf(n, EPS);
  const float scale0 = tanhf(n_cl) / n_cl;  // expmap0 scale

  // Register-cache this wave's view of xs (whole row, 3 float4/lane).
  const float4* xv = (const float4*)xs;
  const float4 x0 = xv[lane];
  const float4 x1 = xv[lane + 64];
  const float4 x2 = xv[lane + 128];

  // Wave w computes rows d = w*16 + r. Coalesced float4 reads of W.
  const float4* Wv = (const float4*)W;  // W[d][h] -> Wv[d*192 + j]
#pragma unroll 4
  for (int r = 0; r < 16; ++r) {
    const int d = w * 16 + r;
    const float4* wr = Wv + (size_t)d * (H / 4);
    float acc = dot4(x0, wr[lane]) + dot4(x1, wr[lane + 64]) +
                dot4(x2, wr[lane + 128]);
    float s = wave_red(acc);
    if (lane == 0) pm[d] = s;
  }
  __syncthreads();

  if (w == 0) {
    const int d = lane;
    float mx = pm[d] * scale0;
    float mnsq = wave_red(mx * mx);
    float mn = fmaxf(sqrtf(mnsq), EPS);
    float xn = fmaxf(scale0 * n, EPS);            // ||expmap0(x)|| = tanh(n)
    float xn_c = fminf(fmaxf(xn, -BND), BND);
    float arg = mn / xn * atanhf(xn_c);
    float s1 = tanhf(arg) / mn;
    out_vecs[(size_t)i * D + d] = s1 * mx;
  }
}

// One wave computes the whole loss: lane = batch row b, loop over D in
// float4s. All reductions are in-register accumulations -- no cross-lane
// shuffles until the final 64-value sum. Replaces the former 16-wave,
// ~1800-ds_bpermute loss block (long serial shuffle chains on one CU).
__global__ __launch_bounds__(64) void loss_only_kernel(
    const float* __restrict__ vecs, float* __restrict__ out) {
  const int b = threadIdx.x;  // 0..63 (= B)
  const float4* v4 = (const float4*)vecs;
  const float4* up = v4 + (size_t)b * (D / 4);
  const float4* vp = v4 + (size_t)(B + b) * (D / 4);
  const float4* np = v4 + (size_t)(2 * B + b * NEG) * (D / 4);

  // Pass 1: scalar moments.
  float u2 = 0.f, v2 = 0.f, uv = 0.f, e2 = 0.f;
  float un2[NEG] = {0.f, 0.f, 0.f, 0.f};
  float uun[NEG] = {0.f, 0.f, 0.f, 0.f};
#pragma unroll
  for (int q = 0; q < D / 4; ++q) {
    const float4 u = up[q], v = vp[q];
    u2 += dot4(u, u);
    v2 += dot4(v, v);
    uv += dot4(u, v);
    const float ex = u.x - v.x, ey = u.y - v.y, ez = u.z - v.z,
                ew = u.w - v.w;
    e2 += ex * ex + ey * ey + ez * ez + ew * ew;
#pragma unroll
    for (int nn = 0; nn < NEG; ++nn) {
      const float4 un = np[(size_t)nn * (D / 4) + q];
      un2[nn] += dot4(un, un);
      uun[nn] += dot4(u, un);
    }
  }

  // mobius_add(-u, y): num = co1*(-u) + co2*y with co1 = 1 - 2<u,y> + |y|^2,
  // co2 = 1 - |u|^2. Pass 2: numerator norms.
  const float co1 = 1.f - 2.f * uv + v2;
  const float co2 = 1.f - u2;
  float c1n[NEG];
#pragma unroll
  for (int nn = 0; nn < NEG; ++nn) c1n[nn] = 1.f - 2.f * uun[nn] + un2[nn];

  float nsq = 0.f;
  float nsqn[NEG] = {0.f, 0.f, 0.f, 0.f};
#pragma unroll
  for (int q = 0; q < D / 4; ++q) {
    const float4 u = up[q], v = vp[q];
    const float ax = co2 * v.x - co1 * u.x;
    const float ay = co2 * v.y - co1 * u.y;
    const float az = co2 * v.z - co1 * u.z;
    const float aw = co2 * v.w - co1 * u.w;
    nsq += ax * ax + ay * ay + az * az + aw * aw;
#pragma unroll
    for (int nn = 0; nn < NEG; ++nn) {
      const float4 un = np[(size_t)nn * (D / 4) + q];
      const float bx = co2 * un.x - c1n[nn] * u.x;
      const float by = co2 * un.y - c1n[nn] * u.y;
      const float bz = co2 * un.z - c1n[nn] * u.z;
      const float bw = co2 * un.w - c1n[nn] * u.w;
      nsqn[nn] += bx * bx + by * by + bz * bz + bw * bw;
    }
  }

  // dist(u, v) = 2*artanh(||mobius_add(-u, v)||)
  const float den = fmaxf(1.f - 2.f * uv + u2 * v2, EPS);
  const float r = sqrtf(nsq) / den;
  const float dsq = 2.f * atanhf(fminf(r, BND));
  const float exp_neg = expf(-dsq);

  float Z1 = 0.f;
#pragma unroll
  for (int nn = 0; nn < NEG; ++nn) {
    const float dnn = fmaxf(1.f - 2.f * uun[nn] + u2 * un2[nn], EPS);
    const float rn = sqrtf(nsqn[nn]) / dnn;
    Z1 += expf(-2.f * atanhf(fminf(rn, BND)));
  }

  // hyperbolic angle at v
  const float norm_v = sqrtf(v2);
  const float euclid = sqrtf(e2);
  const float rad = fmaxf(1.f + u2 * v2 - 2.f * uv, EPS);
  const float den_a = fmaxf(norm_v * euclid * sqrtf(rad), EPS);
  const float cos_ang = (uv * (1.f + v2) - v2 * (1.f + u2)) / den_a;
  const float angle = acosf(fminf(fmaxf(cos_ang, -BND), BND));

  const float ns_loss = -logf(exp_neg / (Z1 + exp_neg));
  // alpha = 0.5: 2*(1-a)*angle + 2*a*ns = angle + ns
  const float tot = wave_red(angle + ns_loss);
  if (b == 0) out[0] = tot / (float)B;
}

extern "C" void kernel_launch(void* const* d_in, const int* in_sizes, int n_in,
                              void* d_out, int out_size, void* d_ws,
                              size_t ws_size, hipStream_t stream) {
  const float* encoded = (const float*)d_in[0];
  const float* n_encoded = (const float*)d_in[1];
  const float* mask1 = (const float*)d_in[2];
  const float* mask2 = (const float*)d_in[3];
  const float* mask_u_neg = (const float*)d_in[4];
  const float* W = (const float*)d_in[5];
  float* vecs = (float*)d_ws;  // NVEC * D floats = 98 KB
  float* out = (float*)d_out;

  gather_matvec_kernel<<<NVEC, 256, 0, stream>>>(
      encoded, n_encoded, mask1, mask2, mask_u_neg, W, vecs);
  loss_only_kernel<<<1, 64, 0, stream>>>(vecs, out);
}